// Round 10
// baseline (63.371 us; speedup 1.0000x reference)
//
#include <hip/hip_runtime.h>
#include <hip/hip_bf16.h>

#define KC 262144

typedef __attribute__((ext_vector_type(8))) short bf16x8;
typedef __attribute__((ext_vector_type(4))) float f32x4;
typedef unsigned short u16;
typedef unsigned int u32;

__device__ __forceinline__ u16 f2bf(float f) {
    u32 u = __float_as_uint(f);
    return (u16)((u + 0x7fffu + ((u >> 16) & 1u)) >> 16);   // RNE (prep)
}
__device__ __forceinline__ u32 pk2(float a, float b) {
    u16 lo = __bfloat16_as_ushort(__float2bfloat16(a));
    u16 hi = __bfloat16_as_ushort(__float2bfloat16(b));
    return (u32)lo | ((u32)hi << 16);
}
__device__ __forceinline__ float bf2f(u32 h) {
    return __uint_as_float(h << 16);
}

// ---------------------------------------------------------------------------
// Single fused kernel. Per block:
//   phase 0: issue tile-0 x loads (hide HBM latency under prep)
//   phase 1: in-block weight prep -> LDS (redundant per block; weights are
//            35KB, L2/L3-resident after first blocks)
//            W1s u16[80][64] | W2s u16[80][96] | W3s u16[16][96] | b1s f32[80]
//   phase 2: barrier; A-frags/b1v -> VGPRs; barrier
//   phase 3: LDS region REUSED as per-wave hst[16][120] + l3s[64][18]
//            r8 main body: 4 tiles x (L1 -> relu -> LDS -> L2 -> relu -> LDS
//            -> L3) with next-tile x prefetch; then per-column expm epilogue.
// LDS union = 28992 B -> 4 blocks/CU at VGPR<=128.
// ---------------------------------------------------------------------------
__global__ __launch_bounds__(256, 2) void mlp_fused(
    const float* __restrict__ x,
    const float* __restrict__ Wo1, const float* __restrict__ bo1,
    const float* __restrict__ Wo2, const float* __restrict__ bo2,
    const float* __restrict__ Wo3, const float* __restrict__ bo3,
    const float* __restrict__ Wt1, const float* __restrict__ bt1,
    const float* __restrict__ Wt2, const float* __restrict__ bt2,
    const float* __restrict__ Wt3, const float* __restrict__ bt3,
    float* __restrict__ out)
{
    __shared__ char lds[28992];
    u16* W1s = (u16*)lds;              // 5120 u16
    u16* W2s = W1s + 5120;             // 7680 u16
    u16* W3s = W2s + 7680;             // 1536 u16
    float* b1s = (float*)(W3s + 1536); // 80 f32 (ends at 28992 B)

    const int tid = threadIdx.x;
    const int wid = tid >> 6;
    const int lane = tid & 63;
    const int g = lane >> 4;
    const int c = lane & 15;
    const int wgid = blockIdx.x * 4 + wid;   // 0..4095
    const int cbase = wgid * 64;

    // reused region (valid after 2nd barrier)
    u16* hstp = (u16*)lds + wid * 1920;          // [16][120] u16 per wave
    u16* l3sp = (u16*)lds + 7680 + wid * 1152;   // [64][18] u16 per wave

    // ---- phase 0: issue tile-0 x loads early ----
    u32 xoff[16];
#pragma unroll
    for (int jj = 0; jj < 16; ++jj) {
        int row = 8 * g + (jj & 7) + 32 * (jj >> 3);
        xoff[jj] = (u32)((row * KC + cbase + c) * 4);
    }
    const char* xb_ = (const char*)x;
    float xr[16];
#pragma unroll
    for (int jj = 0; jj < 16; ++jj)
        xr[jj] = *(const float*)(xb_ + xoff[jj]);

    // ---- phase 1: in-block weight prep -> LDS ----
    for (int i = tid; i < 5120; i += 256) {
        int r = i >> 6, k = i & 63;
        float v = (r < 40) ? Wo1[r * 64 + k] : Wt1[(r - 40) * 64 + k];
        W1s[i] = f2bf(v);
    }
    for (int i = tid; i < 7680; i += 256) {
        int r = i / 96, k = i - r * 96;
        float v = 0.f;
        if (r < 40) {
            if (k < 40) v = Wo2[r * 40 + k];
            else if (k == 80) v = bo2[r];
        } else {
            int rr = r - 40;
            if (k >= 40 && k < 80) v = Wt2[rr * 40 + (k - 40)];
            else if (k == 80) v = bt2[rr];
        }
        W2s[i] = f2bf(v);
    }
    for (int i = tid; i < 1536; i += 256) {
        int r = i / 96, k = i - r * 96;
        float v = 0.f;
        if (r < 9) {
            if (k < 40) v = Wo3[r * 40 + k];
            else if (k == 80) v = bo3[r];
        } else if (r < 12) {
            int rr = r - 9;
            if (k >= 40 && k < 80) v = Wt3[rr * 40 + (k - 40)];
            else if (k == 80) v = bt3[rr];
        }
        W3s[i] = f2bf(v);
    }
    for (int i = tid; i < 80; i += 256)
        b1s[i] = (i < 40) ? bo1[i] : bt1[i - 40];

    __syncthreads();

    // ---- phase 2: A-fragments -> VGPRs ----
    bf16x8 A1[5][2], A3[3];
    f32x4 b1v[5];
#pragma unroll
    for (int m = 0; m < 5; ++m) {
#pragma unroll
        for (int s = 0; s < 2; ++s)
            A1[m][s] = *(const bf16x8*)(W1s + (16 * m + c) * 64 + 32 * s + 8 * g);
        b1v[m] = *(const f32x4*)(b1s + 16 * m + 4 * g);
    }
    bf16x8 A2[5][3];
#pragma unroll
    for (int m = 0; m < 5; ++m)
#pragma unroll
        for (int s = 0; s < 3; ++s)
            if (!(s == 0 && m >= 3))
                A2[m][s] = *(const bf16x8*)(W2s + (16 * m + c) * 96 + 32 * s + 8 * g);
#pragma unroll
    for (int s = 0; s < 3; ++s)
        A3[s] = *(const bf16x8*)(W3s + c * 96 + 32 * s + 8 * g);

    __syncthreads();   // weight region now dead; safe to reuse as hst/l3s

    // ---- ones-row: hst rows 80..95 (row 80 = 1.0, rest 0) ----
    {
        uint2 z;
        z.x = (g == 0) ? 0x00003f80u : 0u;
        z.y = 0u;
        *(uint2*)&hstp[c * 120 + 80 + 4 * g] = z;
    }

    // ---- phase 3: main tile loop (r8 body) ----
#pragma unroll
    for (int t = 0; t < 4; ++t) {
        bf16x8 xv[2];
#pragma unroll
        for (int s = 0; s < 2; ++s) {
            union { u32 u[4]; bf16x8 v; } uu;
#pragma unroll
            for (int p = 0; p < 4; ++p)
                uu.u[p] = pk2(xr[8 * s + 2 * p], xr[8 * s + 2 * p + 1]);
            xv[s] = uu.v;
        }

        // prefetch next tile's x while computing
        float xrn[16];
        if (t < 3) {
#pragma unroll
            for (int jj = 0; jj < 16; ++jj)
                xrn[jj] = *(const float*)(xb_ + (xoff[jj] + (t + 1) * 64));
        }

        // ---- L1 ----
        f32x4 a1[5];
#pragma unroll
        for (int m = 0; m < 5; ++m) a1[m] = b1v[m];
#pragma unroll
        for (int s = 0; s < 2; ++s)
#pragma unroll
            for (int m = 0; m < 5; ++m)
                a1[m] = __builtin_amdgcn_mfma_f32_16x16x32_bf16(
                    A1[m][s], xv[s], a1[m], 0, 0, 0);
#pragma unroll
        for (int m = 0; m < 5; ++m) {
            uint2 w;
            w.x = pk2(fmaxf(a1[m][0], 0.f), fmaxf(a1[m][1], 0.f));
            w.y = pk2(fmaxf(a1[m][2], 0.f), fmaxf(a1[m][3], 0.f));
            *(uint2*)&hstp[c * 120 + 16 * m + 4 * g] = w;
        }

        // ---- L2 (K=96; skip zero block-diag frags m>=3,s=0) ----
        f32x4 a2[5];
#pragma unroll
        for (int m = 0; m < 5; ++m) a2[m] = f32x4{0.f, 0.f, 0.f, 0.f};
#pragma unroll
        for (int s = 0; s < 3; ++s) {
            bf16x8 hb = *(const bf16x8*)&hstp[c * 120 + 32 * s + 8 * g];
#pragma unroll
            for (int m = 0; m < 5; ++m)
                if (!(s == 0 && m >= 3))
                    a2[m] = __builtin_amdgcn_mfma_f32_16x16x32_bf16(
                        A2[m][s], hb, a2[m], 0, 0, 0);
        }
#pragma unroll
        for (int m = 0; m < 5; ++m) {
            uint2 w;
            w.x = pk2(fmaxf(a2[m][0], 0.f), fmaxf(a2[m][1], 0.f));
            w.y = pk2(fmaxf(a2[m][2], 0.f), fmaxf(a2[m][3], 0.f));
            *(uint2*)&hstp[c * 120 + 16 * m + 4 * g] = w;
        }

        // ---- L3 ----
        f32x4 a3 = f32x4{0.f, 0.f, 0.f, 0.f};
#pragma unroll
        for (int s = 0; s < 3; ++s) {
            bf16x8 hb = *(const bf16x8*)&hstp[c * 120 + 32 * s + 8 * g];
            a3 = __builtin_amdgcn_mfma_f32_16x16x32_bf16(
                A3[s], hb, a3, 0, 0, 0);
        }
        {
            uint2 w;
            w.x = pk2(fmaxf(a3[0], 0.f), fmaxf(a3[1], 0.f));
            w.y = pk2(fmaxf(a3[2], 0.f), fmaxf(a3[3], 0.f));
            *(uint2*)&l3sp[(16 * t + c) * 18 + 4 * g] = w;
        }

        if (t < 3) {
#pragma unroll
            for (int jj = 0; jj < 16; ++jj)
                xr[jj] = xrn[jj];
        }
    }

    // ---- per-column epilogue: lane <-> column cbase+lane ----
    {
        uint4 q0 = *(const uint4*)&l3sp[lane * 18];
        uint2 q1 = *(const uint2*)&l3sp[lane * 18 + 8];
        float om[9];
        om[0] = bf2f(q0.x & 0xffffu); om[1] = bf2f(q0.x >> 16);
        om[2] = bf2f(q0.y & 0xffffu); om[3] = bf2f(q0.y >> 16);
        om[4] = bf2f(q0.z & 0xffffu); om[5] = bf2f(q0.z >> 16);
        om[6] = bf2f(q0.w & 0xffffu); om[7] = bf2f(q0.w >> 16);
        om[8] = bf2f(q1.x & 0xffffu);
        float tr0 = bf2f(q1.x >> 16);
        float tr1 = bf2f(q1.y & 0xffffu);
        float tr2 = bf2f(q1.y >> 16);

        const size_t ob = (size_t)cbase + lane;
#pragma unroll
        for (int j = 0; j < 9; ++j)
            out[(size_t)j * KC + ob] = om[j];
        out[(size_t)18 * KC + ob] = tr0;
        out[(size_t)19 * KC + ob] = tr1;
        out[(size_t)20 * KC + ob] = tr2;

        // expm: scale 1/32, Taylor-9 Horner, 5 squarings
        float B[9];
#pragma unroll
        for (int i = 0; i < 9; ++i) B[i] = om[i] * (1.0f / 32.0f);
        float T9[9] = {1.f, 0.f, 0.f, 0.f, 1.f, 0.f, 0.f, 0.f, 1.f};
#pragma unroll
        for (int m = 9; m >= 1; --m) {
            float U[9];
#pragma unroll
            for (int rr = 0; rr < 3; ++rr)
#pragma unroll
                for (int cc = 0; cc < 3; ++cc)
                    U[rr * 3 + cc] = B[rr * 3 + 0] * T9[0 * 3 + cc]
                                   + B[rr * 3 + 1] * T9[1 * 3 + cc]
                                   + B[rr * 3 + 2] * T9[2 * 3 + cc];
            const float s = 1.0f / (float)m;
#pragma unroll
            for (int i = 0; i < 9; ++i)
                T9[i] = U[i] * s + ((i == 0 || i == 4 || i == 8) ? 1.0f : 0.0f);
        }
#pragma unroll
        for (int q = 0; q < 5; ++q) {
            float U[9];
#pragma unroll
            for (int rr = 0; rr < 3; ++rr)
#pragma unroll
                for (int cc = 0; cc < 3; ++cc)
                    U[rr * 3 + cc] = T9[rr * 3 + 0] * T9[0 * 3 + cc]
                                   + T9[rr * 3 + 1] * T9[1 * 3 + cc]
                                   + T9[rr * 3 + 2] * T9[2 * 3 + cc];
#pragma unroll
            for (int i = 0; i < 9; ++i) T9[i] = U[i];
        }
#pragma unroll
        for (int j = 0; j < 9; ++j)
            out[(size_t)(9 + j) * KC + ob] = T9[j];
    }
}

extern "C" void kernel_launch(void* const* d_in, const int* in_sizes, int n_in,
                              void* d_out, int out_size, void* d_ws, size_t ws_size,
                              hipStream_t stream) {
    const float* x   = (const float*)d_in[0];
    const float* Wo1 = (const float*)d_in[1];
    const float* bo1 = (const float*)d_in[2];
    const float* Wo2 = (const float*)d_in[3];
    const float* bo2 = (const float*)d_in[4];
    const float* Wo3 = (const float*)d_in[5];
    const float* bo3 = (const float*)d_in[6];
    const float* Wt1 = (const float*)d_in[7];
    const float* bt1 = (const float*)d_in[8];
    const float* Wt2 = (const float*)d_in[9];
    const float* bt2 = (const float*)d_in[10];
    const float* Wt3 = (const float*)d_in[11];
    const float* bt3 = (const float*)d_in[12];

    float* out = (float*)d_out;

    hipLaunchKernelGGL(mlp_fused, dim3(1024), dim3(256), 0, stream,
                       x, Wo1, bo1, Wo2, bo2, Wo3, bo3,
                       Wt1, bt1, Wt2, bt2, Wt3, bt3, out);
}

// Round 11
// 35.091 us; speedup vs baseline: 1.8059x; 1.8059x over previous
//
#include <hip/hip_runtime.h>
#include <hip/hip_bf16.h>

#define KC 262144

typedef __attribute__((ext_vector_type(8))) short bf16x8;
typedef __attribute__((ext_vector_type(4))) float f32x4;
typedef unsigned short u16;
typedef unsigned int u32;

__device__ __forceinline__ u16 f2bf(float f) {
    u32 u = __float_as_uint(f);
    return (u16)((u + 0x7fffu + ((u >> 16) & 1u)) >> 16);   // RNE (prep)
}
__device__ __forceinline__ u32 pk2(float a, float b) {
    u16 lo = __bfloat16_as_ushort(__float2bfloat16(a));
    u16 hi = __bfloat16_as_ushort(__float2bfloat16(b));
    return (u32)lo | ((u32)hi << 16);
}
__device__ __forceinline__ float bf2f(u32 h) {
    return __uint_as_float(h << 16);
}

// ---------------------------------------------------------------------------
// Prep (r8-proven): stacked bf16 weights in ws.
//   W1s u16[80][64]; W2s u16[80][96]; W3s u16[16][96]; b1s f32[80]
// ---------------------------------------------------------------------------
__global__ __launch_bounds__(256) void prep(
    const float* __restrict__ Wo1, const float* __restrict__ bo1,
    const float* __restrict__ Wo2, const float* __restrict__ bo2,
    const float* __restrict__ Wo3, const float* __restrict__ bo3,
    const float* __restrict__ Wt1, const float* __restrict__ bt1,
    const float* __restrict__ Wt2, const float* __restrict__ bt2,
    const float* __restrict__ Wt3, const float* __restrict__ bt3,
    u16* __restrict__ ws)
{
    u16* W1s = ws;                      // 5120 u16
    u16* W2s = ws + 5120;               // 7680 u16
    u16* W3s = ws + 12800;              // 1536 u16
    float* b1s = (float*)(ws + 14336);  // 80 f32
    const int t0 = blockIdx.x * 256 + threadIdx.x;
    const int NT = gridDim.x * 256;

    for (int i = t0; i < 5120; i += NT) {
        int r = i >> 6, k = i & 63;
        float v = (r < 40) ? Wo1[r * 64 + k] : Wt1[(r - 40) * 64 + k];
        W1s[i] = f2bf(v);
    }
    for (int i = t0; i < 7680; i += NT) {
        int r = i / 96, k = i - r * 96;
        float v = 0.f;
        if (r < 40) {
            if (k < 40) v = Wo2[r * 40 + k];
            else if (k == 80) v = bo2[r];
        } else {
            int rr = r - 40;
            if (k >= 40 && k < 80) v = Wt2[rr * 40 + (k - 40)];
            else if (k == 80) v = bt2[rr];
        }
        W2s[i] = f2bf(v);
    }
    for (int i = t0; i < 1536; i += NT) {
        int r = i / 96, k = i - r * 96;
        float v = 0.f;
        if (r < 9) {
            if (k < 40) v = Wo3[r * 40 + k];
            else if (k == 80) v = bo3[r];
        } else if (r < 12) {
            int rr = r - 9;
            if (k >= 40 && k < 80) v = Wt3[rr * 40 + (k - 40)];
            else if (k == 80) v = bt3[rr];
        }
        W3s[i] = f2bf(v);
    }
    for (int i = t0; i < 80; i += NT)
        b1s[i] = (i < 40) ? bo1[i] : bt1[i - 40];
}

// ---------------------------------------------------------------------------
// In-register transpose: packed MFMA C-output pairs P[m] (m=0..4, 80 rows)
// -> B-fragments hb[3] (K=96 incl. ones-row at row 80).
// Derivation: frag s reg p on lane (g,c) holds rows (32s+8g+2p, +1), col c.
// Row 16m+4q+j lives as comp (j>>1 ? y:x) of P[m] on lane 16q+c.
//  -> m = 2s+(g>>1); q = 2(g&1)+(p>>1); comp = p&1.
// Verified: e.g. s=1,g=3,c=5,p=3 -> rows 62,63 = P[3].y from lane 53. ✓
// ---------------------------------------------------------------------------
__device__ __forceinline__ void transpose_h(
    const u32* Px, const u32* Py, int g, int c, bf16x8* hb)
{
    const int srcA = 16 * (2 * (g & 1)) + c;   // p = 0,1
    const int srcB = srcA + 16;                // p = 2,3
    const bool hiM = (g >= 2);
#pragma unroll
    for (int s = 0; s < 2; ++s) {
        union { u32 u[4]; bf16x8 v; } uu;
        u32 a0 = (u32)__shfl((int)Px[2 * s], srcA);
        u32 b0 = (u32)__shfl((int)Px[2 * s + 1], srcA);
        uu.u[0] = hiM ? b0 : a0;
        u32 a1 = (u32)__shfl((int)Py[2 * s], srcA);
        u32 b1 = (u32)__shfl((int)Py[2 * s + 1], srcA);
        uu.u[1] = hiM ? b1 : a1;
        u32 a2 = (u32)__shfl((int)Px[2 * s], srcB);
        u32 b2 = (u32)__shfl((int)Px[2 * s + 1], srcB);
        uu.u[2] = hiM ? b2 : a2;
        u32 a3 = (u32)__shfl((int)Py[2 * s], srcB);
        u32 b3 = (u32)__shfl((int)Py[2 * s + 1], srcB);
        uu.u[3] = hiM ? b3 : a3;
        hb[s] = uu.v;
    }
    {   // s=2: rows 64..95. g<2 -> P[4] (rows 64..79); g>=2 -> row80=1.0, rest 0
        union { u32 u[4]; bf16x8 v; } uu;
        u32 v0 = (u32)__shfl((int)Px[4], srcA);
        u32 v1 = (u32)__shfl((int)Py[4], srcA);
        u32 v2 = (u32)__shfl((int)Px[4], srcB);
        u32 v3 = (u32)__shfl((int)Py[4], srcB);
        u32 k0 = (g == 2) ? 0x00003f80u : 0u;   // rows 80,81 -> (1.0, 0)
        uu.u[0] = hiM ? k0 : v0;
        uu.u[1] = hiM ? 0u : v1;
        uu.u[2] = hiM ? 0u : v2;
        uu.u[3] = hiM ? 0u : v3;
        hb[2] = uu.v;
    }
}

// ---------------------------------------------------------------------------
// Main: one wave = 64 cols (4 tiles). ZERO LDS, zero barriers: the h / h2
// redistributions between layers are in-register shuffle-transposes, and the
// L3->epilogue hand-off is the r9-verified shfl redistribution.
// ---------------------------------------------------------------------------
__global__ __launch_bounds__(256, 2) void mlp_shfl(
    const float* __restrict__ x, const u16* __restrict__ ws,
    float* __restrict__ out)
{
    const u16* W1s = ws;
    const u16* W2s = ws + 5120;
    const u16* W3s = ws + 12800;
    const float* b1s = (const float*)(ws + 14336);

    const int tid = threadIdx.x;
    const int wid = tid >> 6;
    const int lane = tid & 63;
    const int g = lane >> 4;
    const int c = lane & 15;
    const int wgid = blockIdx.x * 4 + wid;   // 0..4095
    const int cbase = wgid * 64;

    // ---- A-fragments (weights) ----
    bf16x8 A1[5][2], A3[3];
    f32x4 b1v[5];
#pragma unroll
    for (int m = 0; m < 5; ++m) {
#pragma unroll
        for (int s = 0; s < 2; ++s)
            A1[m][s] = *(const bf16x8*)(W1s + (16 * m + c) * 64 + 32 * s + 8 * g);
        b1v[m] = *(const f32x4*)(b1s + 16 * m + 4 * g);
    }
    bf16x8 A2[5][3];
#pragma unroll
    for (int m = 0; m < 5; ++m)
#pragma unroll
        for (int s = 0; s < 3; ++s)
            if (!(s == 0 && m >= 3))
                A2[m][s] = *(const bf16x8*)(W2s + (16 * m + c) * 96 + 32 * s + 8 * g);
#pragma unroll
    for (int s = 0; s < 3; ++s)
        A3[s] = *(const bf16x8*)(W3s + c * 96 + 32 * s + 8 * g);

    // ---- per-lane x byte offsets (B-frag pattern) ----
    u32 xoff[16];
#pragma unroll
    for (int jj = 0; jj < 16; ++jj) {
        int row = 8 * g + (jj & 7) + 32 * (jj >> 3);
        xoff[jj] = (u32)((row * KC + cbase + c) * 4);
    }
    const char* xb_ = (const char*)x;

    float xr[16];
#pragma unroll
    for (int jj = 0; jj < 16; ++jj)
        xr[jj] = *(const float*)(xb_ + xoff[jj]);

    u32 w0[4], w1[4];   // L3 outputs per tile

#pragma unroll
    for (int t = 0; t < 4; ++t) {
        bf16x8 xv[2];
#pragma unroll
        for (int s = 0; s < 2; ++s) {
            union { u32 u[4]; bf16x8 v; } uu;
#pragma unroll
            for (int p = 0; p < 4; ++p)
                uu.u[p] = pk2(xr[8 * s + 2 * p], xr[8 * s + 2 * p + 1]);
            xv[s] = uu.v;
        }

        float xrn[16];
        if (t < 3) {
#pragma unroll
            for (int jj = 0; jj < 16; ++jj)
                xrn[jj] = *(const float*)(xb_ + (xoff[jj] + (t + 1) * 64));
        }

        // ---- L1 ----
        f32x4 a1[5];
#pragma unroll
        for (int m = 0; m < 5; ++m) a1[m] = b1v[m];
#pragma unroll
        for (int s = 0; s < 2; ++s)
#pragma unroll
            for (int m = 0; m < 5; ++m)
                a1[m] = __builtin_amdgcn_mfma_f32_16x16x32_bf16(
                    A1[m][s], xv[s], a1[m], 0, 0, 0);

        u32 Px[5], Py[5];
#pragma unroll
        for (int m = 0; m < 5; ++m) {
            Px[m] = pk2(fmaxf(a1[m][0], 0.f), fmaxf(a1[m][1], 0.f));
            Py[m] = pk2(fmaxf(a1[m][2], 0.f), fmaxf(a1[m][3], 0.f));
        }
        bf16x8 hb[3];
        transpose_h(Px, Py, g, c, hb);

        // ---- L2 (K=96; skip zero block-diag frags m>=3,s=0) ----
        f32x4 a2[5];
#pragma unroll
        for (int m = 0; m < 5; ++m) a2[m] = f32x4{0.f, 0.f, 0.f, 0.f};
#pragma unroll
        for (int s = 0; s < 3; ++s)
#pragma unroll
            for (int m = 0; m < 5; ++m)
                if (!(s == 0 && m >= 3))
                    a2[m] = __builtin_amdgcn_mfma_f32_16x16x32_bf16(
                        A2[m][s], hb[s], a2[m], 0, 0, 0);
#pragma unroll
        for (int m = 0; m < 5; ++m) {
            Px[m] = pk2(fmaxf(a2[m][0], 0.f), fmaxf(a2[m][1], 0.f));
            Py[m] = pk2(fmaxf(a2[m][2], 0.f), fmaxf(a2[m][3], 0.f));
        }
        transpose_h(Px, Py, g, c, hb);

        // ---- L3 ----
        f32x4 a3 = f32x4{0.f, 0.f, 0.f, 0.f};
#pragma unroll
        for (int s = 0; s < 3; ++s)
            a3 = __builtin_amdgcn_mfma_f32_16x16x32_bf16(
                A3[s], hb[s], a3, 0, 0, 0);

        w0[t] = pk2(fmaxf(a3[0], 0.f), fmaxf(a3[1], 0.f));   // rows 4g,4g+1
        w1[t] = pk2(fmaxf(a3[2], 0.f), fmaxf(a3[3], 0.f));   // rows 4g+2,4g+3

        if (t < 3) {
#pragma unroll
            for (int jj = 0; jj < 16; ++jj)
                xr[jj] = xrn[jj];
        }
    }

    // ---- epilogue: r9-verified shfl redistribution + expm ----
    {
        const int T = lane >> 4;
        const int cp = lane & 15;
        const int s0 = cp, s1 = 16 + cp, s2 = 32 + cp;

        auto selT = [&](u32 v0, u32 v1, u32 v2, u32 v3) -> u32 {
            u32 lo = (T & 1) ? v1 : v0;
            u32 hi = (T & 1) ? v3 : v2;
            return (T & 2) ? hi : lo;
        };
        u32 q0 = selT((u32)__shfl((int)w0[0], s0), (u32)__shfl((int)w0[1], s0),
                      (u32)__shfl((int)w0[2], s0), (u32)__shfl((int)w0[3], s0)); // rows 0,1
        u32 q1 = selT((u32)__shfl((int)w1[0], s0), (u32)__shfl((int)w1[1], s0),
                      (u32)__shfl((int)w1[2], s0), (u32)__shfl((int)w1[3], s0)); // rows 2,3
        u32 q2 = selT((u32)__shfl((int)w0[0], s1), (u32)__shfl((int)w0[1], s1),
                      (u32)__shfl((int)w0[2], s1), (u32)__shfl((int)w0[3], s1)); // rows 4,5
        u32 q3 = selT((u32)__shfl((int)w1[0], s1), (u32)__shfl((int)w1[1], s1),
                      (u32)__shfl((int)w1[2], s1), (u32)__shfl((int)w1[3], s1)); // rows 6,7
        u32 q4 = selT((u32)__shfl((int)w0[0], s2), (u32)__shfl((int)w0[1], s2),
                      (u32)__shfl((int)w0[2], s2), (u32)__shfl((int)w0[3], s2)); // rows 8,9
        u32 q5 = selT((u32)__shfl((int)w1[0], s2), (u32)__shfl((int)w1[1], s2),
                      (u32)__shfl((int)w1[2], s2), (u32)__shfl((int)w1[3], s2)); // rows 10,11

        float om[9];
        om[0] = bf2f(q0 & 0xffffu); om[1] = bf2f(q0 >> 16);
        om[2] = bf2f(q1 & 0xffffu); om[3] = bf2f(q1 >> 16);
        om[4] = bf2f(q2 & 0xffffu); om[5] = bf2f(q2 >> 16);
        om[6] = bf2f(q3 & 0xffffu); om[7] = bf2f(q3 >> 16);
        om[8] = bf2f(q4 & 0xffffu);
        float tr0 = bf2f(q4 >> 16);
        float tr1 = bf2f(q5 & 0xffffu);
        float tr2 = bf2f(q5 >> 16);

        const size_t ob = (size_t)cbase + lane;
#pragma unroll
        for (int j = 0; j < 9; ++j)
            out[(size_t)j * KC + ob] = om[j];
        out[(size_t)18 * KC + ob] = tr0;
        out[(size_t)19 * KC + ob] = tr1;
        out[(size_t)20 * KC + ob] = tr2;

        // expm: scale 1/32, Taylor-9 Horner, 5 squarings
        float B[9];
#pragma unroll
        for (int i = 0; i < 9; ++i) B[i] = om[i] * (1.0f / 32.0f);
        float T9[9] = {1.f, 0.f, 0.f, 0.f, 1.f, 0.f, 0.f, 0.f, 1.f};
#pragma unroll
        for (int m = 9; m >= 1; --m) {
            float U[9];
#pragma unroll
            for (int rr = 0; rr < 3; ++rr)
#pragma unroll
                for (int cc = 0; cc < 3; ++cc)
                    U[rr * 3 + cc] = B[rr * 3 + 0] * T9[0 * 3 + cc]
                                   + B[rr * 3 + 1] * T9[1 * 3 + cc]
                                   + B[rr * 3 + 2] * T9[2 * 3 + cc];
            const float s = 1.0f / (float)m;
#pragma unroll
            for (int i = 0; i < 9; ++i)
                T9[i] = U[i] * s + ((i == 0 || i == 4 || i == 8) ? 1.0f : 0.0f);
        }
#pragma unroll
        for (int q = 0; q < 5; ++q) {
            float U[9];
#pragma unroll
            for (int rr = 0; rr < 3; ++rr)
#pragma unroll
                for (int cc = 0; cc < 3; ++cc)
                    U[rr * 3 + cc] = T9[rr * 3 + 0] * T9[0 * 3 + cc]
                                   + T9[rr * 3 + 1] * T9[1 * 3 + cc]
                                   + T9[rr * 3 + 2] * T9[2 * 3 + cc];
#pragma unroll
            for (int i = 0; i < 9; ++i) T9[i] = U[i];
        }
#pragma unroll
        for (int j = 0; j < 9; ++j)
            out[(size_t)(9 + j) * KC + ob] = T9[j];
    }
}

extern "C" void kernel_launch(void* const* d_in, const int* in_sizes, int n_in,
                              void* d_out, int out_size, void* d_ws, size_t ws_size,
                              hipStream_t stream) {
    const float* x   = (const float*)d_in[0];
    const float* Wo1 = (const float*)d_in[1];
    const float* bo1 = (const float*)d_in[2];
    const float* Wo2 = (const float*)d_in[3];
    const float* bo2 = (const float*)d_in[4];
    const float* Wo3 = (const float*)d_in[5];
    const float* bo3 = (const float*)d_in[6];
    const float* Wt1 = (const float*)d_in[7];
    const float* bt1 = (const float*)d_in[8];
    const float* Wt2 = (const float*)d_in[9];
    const float* bt2 = (const float*)d_in[10];
    const float* Wt3 = (const float*)d_in[11];
    const float* bt3 = (const float*)d_in[12];

    u16* ws = (u16*)d_ws;
    float* out = (float*)d_out;

    hipLaunchKernelGGL(prep, dim3(16), dim3(256), 0, stream,
                       Wo1, bo1, Wo2, bo2, Wo3, bo3,
                       Wt1, bt1, Wt2, bt2, Wt3, bt3, ws);
    hipLaunchKernelGGL(mlp_shfl, dim3(1024), dim3(256), 0, stream,
                       x, ws, out);
}